// Round 14
// baseline (238.886 us; speedup 1.0000x reference)
//
#include <hip/hip_runtime.h>
#include <cstdint>

// CausalSelfAttention fused pipeline, all-bf16 MFMA path.
// R14: grid-level parallelism for attn. R13's 1024x4-wave grid capped occupancy
// at 16 waves/CU (39% measured) while VGPR=60 permits 32/CU. New shape:
// block = 4 waves = 4 BATCHES of the same (h,q16) slab (uniform by construction),
// 2048 blocks big-first (LPT backfill), h=bid&7 keeps head's relt on one XCD,
// 4 waves share relt tiles through L1. launch_bounds(256,6) — no allocator squeeze;
// R13-shape body emits ~60 VGPR -> 8 waves/EU at runtime.
// ws layout (ushort): Qf[8.39M] Kf[8.39M] Vf[8.39M] XbAO[8.39M] WtQ[786K] WtO[262K] [relt 33.55M]

#define DEVI __device__ __forceinline__

typedef __bf16 bf8 __attribute__((ext_vector_type(8)));
typedef float f4 __attribute__((ext_vector_type(4)));
typedef unsigned short us8 __attribute__((ext_vector_type(8)));
typedef unsigned short us4 __attribute__((ext_vector_type(4)));

typedef const unsigned int __attribute__((address_space(1))) gu32;
typedef unsigned int __attribute__((address_space(3))) lu32;

DEVI unsigned short f2bf(float f) {  // RNE f32->bf16 (prep/GEMM epilogues)
  unsigned u = __builtin_bit_cast(unsigned, f);
  u += 0x7fffu + ((u >> 16) & 1u);
  return (unsigned short)(u >> 16);
}

DEVI unsigned short cbf(float f) {   // compiler-lowered cast (v_cvt_pk_bf16_f32 pairs)
  return __builtin_bit_cast(unsigned short, (__bf16)f);
}

DEVI void gl_lds16(const void* g, void* l) {
  __builtin_amdgcn_global_load_lds((gu32*)g, (lu32*)l, 16, 0, 0);
}

DEVI bf8 comb(us4 a, us4 b) {
  us8 r;
  r[0]=a[0]; r[1]=a[1]; r[2]=a[2]; r[3]=a[3];
  r[4]=b[0]; r[5]=b[1]; r[6]=b[2]; r[7]=b[3];
  return __builtin_bit_cast(bf8, r);
}

// ---------------- prep: x (f32 [16384][512]) -> bf16, chunk-swizzled ----------------
__global__ __launch_bounds__(256) void k_convert_x(const float* __restrict__ x,
                                                   unsigned short* __restrict__ xb) {
  int c = blockIdx.x * 256 + threadIdx.x;   // 1,048,576 chunks
  int row = c >> 6, cl = c & 63;
  const float* s = x + ((size_t)row << 9) + (cl << 3);
  float4 a = *(const float4*)s;
  float4 b = *(const float4*)(s + 4);
  us8 o;
  o[0]=f2bf(a.x); o[1]=f2bf(a.y); o[2]=f2bf(a.z); o[3]=f2bf(a.w);
  o[4]=f2bf(b.x); o[5]=f2bf(b.y); o[6]=f2bf(b.z); o[7]=f2bf(b.w);
  int p = (cl & ~7) | ((cl & 7) ^ (row & 7));
  *(us8*)(xb + ((size_t)row << 9) + (p << 3)) = o;
}

// ------------- prep: W [512][N] f32 -> Wt [N][512] bf16, chunk-swizzled -------------
__global__ __launch_bounds__(256) void k_transpose_w(const float* __restrict__ W,
                                                     unsigned short* __restrict__ Wt, int N) {
  __shared__ float t[32][33];
  int k0 = blockIdx.x * 32, n0 = blockIdx.y * 32;
  int tx = threadIdx.x & 31, ty = threadIdx.x >> 5;
#pragma unroll
  for (int r = 0; r < 4; ++r)
    t[ty + r * 8][tx] = W[(size_t)(k0 + ty + r * 8) * N + n0 + tx];
  __syncthreads();
#pragma unroll
  for (int r = 0; r < 4; ++r) {
    int n = n0 + ty + r * 8, k = k0 + tx;
    int k2 = (k & ~63) | ((((k >> 3) & 7) ^ (n & 7)) << 3) | (k & 7);
    Wt[((size_t)n << 9) + k2] = f2bf(t[tx][ty + r * 8]);
  }
}

// ---- prep: rel f32 [h][q][k] -> bf16 fragment-ordered table (lower-tri tiles only) ----
__global__ __launch_bounds__(256) void k_relconv(const float* __restrict__ rel,
                                                 unsigned short* __restrict__ relt) {
  int t = blockIdx.x * 256 + threadIdx.x;   // 8.39M threads
  int lane = t & 63, ct = (t >> 6) & 3, kt = (t >> 8) & 31, q16 = (t >> 13) & 127, h = t >> 20;
  if (kt > (q16 >> 2)) return;              // above-diagonal tiles never read
  int row0 = (q16 << 4) + ((lane >> 4) << 2);
  int col = (kt << 6) + (ct << 4) + (lane & 15);
  const float* rp = rel + ((size_t)h << 22) + ((size_t)row0 << 11) + col;
  us4 o;
#pragma unroll
  for (int j = 0; j < 4; ++j) o[j] = f2bf(rp[(size_t)j << 11]);
  size_t idx = ((((((size_t)h << 7) | q16) << 5) | kt) << 2 | ct) << 6 | lane;
  *(us4*)(relt + (idx << 2)) = o;
}

// ---------------- GEMM: C[M][col] = A[M][512] * Bt[col][512]^T + bias ----------------
template <int EPI>
__global__ __launch_bounds__(256, 2)
void k_gemm(const unsigned short* __restrict__ Ag, const unsigned short* __restrict__ Bg,
            const float* __restrict__ bias, float* __restrict__ Of,
            unsigned short* __restrict__ Oq, unsigned short* __restrict__ Ok,
            unsigned short* __restrict__ Ov) {
  __shared__ __align__(16) unsigned short lds[128 * 64 * 2];
  unsigned short* Al = lds;
  unsigned short* Bl = lds + 128 * 64;
  const int tid = threadIdx.x, wv = tid >> 6, lane = tid & 63, g = lane >> 4, cl = lane & 15;
  const int wm = wv >> 1, wn = wv & 1;
  const int row0 = blockIdx.x * 128, col0 = blockIdx.y * 128;
  f4 acc[4][4];
#pragma unroll
  for (int i = 0; i < 4; ++i)
#pragma unroll
    for (int j = 0; j < 4; ++j) acc[i][j] = (f4){0.f, 0.f, 0.f, 0.f};

  for (int kt = 0; kt < 8; ++kt) {
#pragma unroll
    for (int j = 0; j < 4; ++j) {
      int ci = wv * 4 + j;
      int gci = ci * 64 + lane;
      int r = gci >> 3, cc = gci & 7;
      gl_lds16(Ag + ((size_t)(row0 + r) << 9) + kt * 64 + cc * 8, Al + ci * 512);
      gl_lds16(Bg + ((size_t)(col0 + r) << 9) + kt * 64 + cc * 8, Bl + ci * 512);
    }
    __syncthreads();
#pragma unroll
    for (int kk = 0; kk < 2; ++kk) {
      bf8 af[4], bb[4];
#pragma unroll
      for (int mf = 0; mf < 4; ++mf) {
        int r = wm * 64 + mf * 16 + cl;
        int cc = (kk * 4 + g) ^ (r & 7);
        af[mf] = *(const bf8*)(Al + r * 64 + cc * 8);
      }
#pragma unroll
      for (int nf = 0; nf < 4; ++nf) {
        int r = wn * 64 + nf * 16 + cl;
        int cc = (kk * 4 + g) ^ (r & 7);
        bb[nf] = *(const bf8*)(Bl + r * 64 + cc * 8);
      }
#pragma unroll
      for (int mf = 0; mf < 4; ++mf)
#pragma unroll
        for (int nf = 0; nf < 4; ++nf)
          acc[mf][nf] = __builtin_amdgcn_mfma_f32_16x16x32_bf16(af[mf], bb[nf], acc[mf][nf], 0, 0, 0);
    }
    __syncthreads();
  }

  if (EPI == 1) {
#pragma unroll
    for (int nf = 0; nf < 4; ++nf) {
      int col = col0 + wn * 64 + nf * 16 + cl;
      float bv = bias[col];
#pragma unroll
      for (int mf = 0; mf < 4; ++mf) {
#pragma unroll
        for (int j = 0; j < 4; ++j) {
          int row = row0 + wm * 64 + mf * 16 + 4 * g + j;  // C/D: col=lane&15, row=4*(lane>>4)+reg
          Of[((size_t)row << 9) + col] = acc[mf][nf][j] + bv;
        }
      }
    }
  } else {
    const int which = col0 >> 9;   // block-uniform
#pragma unroll
    for (int nf = 0; nf < 4; ++nf) {
      int col = col0 + wn * 64 + nf * 16 + cl;
      float bv = bias[col];
      int d = col & 63, h = (col >> 6) & 7;
#pragma unroll
      for (int mf = 0; mf < 4; ++mf) {
        int row = row0 + wm * 64 + mf * 16 + 4 * g;   // j = 0 row
        int b = row >> 11, s = row & 2047;
        size_t fb = ((size_t)b * 8 + h) * 131072;     // per-(b,h) fragment array
        if (which == 0) {
          // Q frag: [q16][kk][lane][8]; val = Q[s=q16*16+cl][d=kk*32+g*8+j]
#pragma unroll
          for (int j = 0; j < 4; ++j) {
            int ss = s + j;
            size_t off = fb + (size_t)((ss >> 4) * 1024 + (d >> 5) * 512 +
                                       (((d >> 3) & 3) * 16 + (ss & 15)) * 8 + (d & 7));
            Oq[off] = f2bf((acc[mf][nf][j] + bv) * 0.125f);   // fold softmax scale
          }
        } else if (which == 1) {
          // K frag: [kt][kk][ct][lane][8]; val = K[s=kt*64+ct*16+cl][d=kk*32+g*8+j]
#pragma unroll
          for (int j = 0; j < 4; ++j) {
            int ss = s + j;
            size_t off = fb + (size_t)((ss >> 6) * 4096 + (d >> 5) * 2048 + ((ss >> 4) & 3) * 512 +
                                       (((d >> 3) & 3) * 16 + (ss & 15)) * 8 + (d & 7));
            Ok[off] = f2bf(acc[mf][nf][j] + bv);
          }
        } else {
          // V frag: [kt][kk][ct][lane][8]; val = V[s=kt*64+kk*32+g*8+j][d=ct*16+cl]
          us4 o;
#pragma unroll
          for (int j = 0; j < 4; ++j) o[j] = f2bf(acc[mf][nf][j] + bv);
          size_t off = fb + (size_t)((s >> 6) * 4096 + ((s >> 5) & 1) * 2048 + (d >> 4) * 512 +
                                     ((((s >> 3) & 3) * 16) + (d & 15)) * 8 + (s & 7));
          *(us4*)(Ov + off) = o;
        }
      }
    }
  }
}

// ------------------------------- flash attention --------------------------------
// block = 4 waves = 4 BATCHES of the same (h, q16) slab; 2048 blocks big-first.
// Each wave: one q16 slab, k-tiles 0..(q16>>2). relt tiles identical across the
// block's 4 waves (L1-shared). Loads at tile top (K then V then rel, FIFO vmcnt).
template <bool RELT>
__global__ __launch_bounds__(256, 6)
void k_attn(const unsigned short* __restrict__ Qf, const unsigned short* __restrict__ Kf,
            const unsigned short* __restrict__ Vf, const float* __restrict__ rel,
            const unsigned short* __restrict__ relt, unsigned short* __restrict__ AO) {
  __shared__ __align__(16) unsigned short Pl[4][16 * 68];
  const int tid = threadIdx.x, wv = tid >> 6, lane = tid & 63, g = lane >> 4, cl = lane & 15;
  // decode: h = bid&7 (all blocks of head h share bid%8 -> one XCD holds relt[h]);
  // q16 big-first; wave's batch = (rest&1)*4 + wv.
  int bid = blockIdx.x;                        // 2048 blocks
  int h = bid & 7;
  int rest = bid >> 3;                         // 0..255
  int q16 = 127 - (rest >> 1);                 // 127..0, big-first
  int b = ((rest & 1) << 2) | wv;              // 0..7
  const int rX = q16 << 4;
  const int ktop = q16 >> 2;                   // diagonal k-tile index
  size_t fb = (((size_t)b << 3) + h) * 131072;
  const unsigned short* Qp = Qf + fb;
  const unsigned short* Kp = Kf + fb;
  const unsigned short* Vp = Vf + fb;
  const float* relp = rel + ((size_t)h << 22);
  unsigned short* pw = Pl[wv];

  bf8 qf[2];
#pragma unroll
  for (int kk = 0; kk < 2; ++kk)
    qf[kk] = *(const bf8*)(Qp + q16 * 1024 + kk * 512 + lane * 8);

  f4 oa[4];
  float mr[4], lr[4];
#pragma unroll
  for (int j = 0; j < 4; ++j) { mr[j] = -1e30f; lr[j] = 0.f; }
#pragma unroll
  for (int ct = 0; ct < 4; ++ct) oa[ct] = (f4){0.f, 0.f, 0.f, 0.f};

  for (int kt = 0; kt <= ktop; ++kt) {
    const int kb = kt << 6;
    const unsigned short* Kt = Kp + kt * 4096;
    const unsigned short* Vt = Vp + kt * 4096;
    // ---- ALL loads up front: K (QK^T dep), then V, then rel (FIFO vmcnt) ----
    bf8 kf[2][4], vf[2][4];
#pragma unroll
    for (int kk = 0; kk < 2; ++kk)
#pragma unroll
      for (int ct = 0; ct < 4; ++ct)
        kf[kk][ct] = *(const bf8*)(Kt + kk * 2048 + ct * 512 + lane * 8);
#pragma unroll
    for (int kk = 0; kk < 2; ++kk)
#pragma unroll
      for (int ct = 0; ct < 4; ++ct)
        vf[kk][ct] = *(const bf8*)(Vt + kk * 2048 + ct * 512 + lane * 8);
    us4 rt4[4];
    float rl[4][4];
    if constexpr (RELT) {
      const unsigned short* tb = relt + (((((size_t)h << 7) | q16) << 5) | kt) * 1024;
#pragma unroll
      for (int ct = 0; ct < 4; ++ct)
        rt4[ct] = *(const us4*)(tb + ((ct << 6) | lane) * 4);
    } else {
      const float* rb = relp + ((size_t)(rX + 4 * g) << 11) + kb + cl;
#pragma unroll
      for (int ct = 0; ct < 4; ++ct)
#pragma unroll
        for (int j = 0; j < 4; ++j) rl[ct][j] = rb[((size_t)j << 11) + ct * 16];
    }
    // ---- QK^T (waits on kf only) ----
    f4 sa[4];
#pragma unroll
    for (int ct = 0; ct < 4; ++ct) sa[ct] = (f4){0.f, 0.f, 0.f, 0.f};
#pragma unroll
    for (int kk = 0; kk < 2; ++kk)
#pragma unroll
      for (int ct = 0; ct < 4; ++ct)
        sa[ct] = __builtin_amdgcn_mfma_f32_16x16x32_bf16(qf[kk], kf[kk][ct], sa[ct], 0, 0, 0);
    // ---- rel_pos add ----
    if constexpr (RELT) {
#pragma unroll
      for (int ct = 0; ct < 4; ++ct)
#pragma unroll
        for (int j = 0; j < 4; ++j)
          sa[ct][j] += __builtin_bit_cast(float, (unsigned)rt4[ct][j] << 16);
    } else {
#pragma unroll
      for (int ct = 0; ct < 4; ++ct)
#pragma unroll
        for (int j = 0; j < 4; ++j) sa[ct][j] += rl[ct][j];
    }
    // ---- causal mask (diagonal tile only) ----
    if (kt == ktop) {
#pragma unroll
      for (int ct = 0; ct < 4; ++ct) {
        int kcol = kb + ct * 16 + cl;
#pragma unroll
        for (int j = 0; j < 4; ++j)
          if (kcol > rX + 4 * g + j) sa[ct][j] = -1e30f;
      }
    }
    // ---- online softmax (rows in 16-lane groups) ----
    float al[4];
#pragma unroll
    for (int j = 0; j < 4; ++j) {
      float m0 = fmaxf(fmaxf(sa[0][j], sa[1][j]), fmaxf(sa[2][j], sa[3][j]));
      m0 = fmaxf(m0, __shfl_xor(m0, 1, 16));
      m0 = fmaxf(m0, __shfl_xor(m0, 2, 16));
      m0 = fmaxf(m0, __shfl_xor(m0, 4, 16));
      m0 = fmaxf(m0, __shfl_xor(m0, 8, 16));
      float mn = fmaxf(mr[j], m0);
      al[j] = __expf(mr[j] - mn);
      mr[j] = mn;
    }
#pragma unroll
    for (int ct = 0; ct < 4; ++ct)
#pragma unroll
      for (int j = 0; j < 4; ++j) sa[ct][j] = __expf(sa[ct][j] - mr[j]);
#pragma unroll
    for (int j = 0; j < 4; ++j) {
      float rs = sa[0][j] + sa[1][j] + sa[2][j] + sa[3][j];
      rs += __shfl_xor(rs, 1, 16);
      rs += __shfl_xor(rs, 2, 16);
      rs += __shfl_xor(rs, 4, 16);
      rs += __shfl_xor(rs, 8, 16);
      lr[j] = lr[j] * al[j] + rs;
    }
#pragma unroll
    for (int ct = 0; ct < 4; ++ct) {
      oa[ct][0] *= al[0]; oa[ct][1] *= al[1]; oa[ct][2] *= al[2]; oa[ct][3] *= al[3];
    }
    // ---- P -> LDS transpose (wave-private; compiler cvt_pk pairs) ----
#pragma unroll
    for (int ct = 0; ct < 4; ++ct)
#pragma unroll
      for (int j = 0; j < 4; ++j)
        pw[(4 * g + j) * 68 + ct * 16 + cl] = cbf(sa[ct][j]);
    // ---- PV (vf already resident) ----
#pragma unroll
    for (int kk = 0; kk < 2; ++kk) {
      us4 p0 = *(const us4*)(pw + cl * 68 + kk * 32 + g * 8);
      us4 p1 = *(const us4*)(pw + cl * 68 + kk * 32 + g * 8 + 4);
      bf8 pf = comb(p0, p1);
#pragma unroll
      for (int ct = 0; ct < 4; ++ct)
        oa[ct] = __builtin_amdgcn_mfma_f32_16x16x32_bf16(pf, vf[kk][ct], oa[ct], 0, 0, 0);
    }
  }
  // ---- epilogue: O /= l, chunk-swizzled bf16 write ----
#pragma unroll
  for (int j = 0; j < 4; ++j) {
    float inv = 1.0f / lr[j];
    int s = rX + 4 * g + j;
#pragma unroll
    for (int ct = 0; ct < 4; ++ct) {
      int d = ct * 16 + cl;
      int d2 = (d & 7) | (((d >> 3) ^ (s & 7)) << 3);
      AO[(((size_t)b << 11) + s) * 512 + h * 64 + d2] = cbf(oa[ct][j] * inv);
    }
  }
}

// ------------------------------------ launch ------------------------------------
extern "C" void kernel_launch(void* const* d_in, const int* in_sizes, int n_in,
                              void* d_out, int out_size, void* d_ws, size_t ws_size,
                              hipStream_t stream) {
  const float* x    = (const float*)d_in[0];
  const float* Wqkv = (const float*)d_in[1];
  const float* bqkv = (const float*)d_in[2];
  const float* Wout = (const float*)d_in[3];
  const float* bout = (const float*)d_in[4];
  const float* rel  = (const float*)d_in[5];
  float* out = (float*)d_out;

  unsigned short* Qw  = (unsigned short*)d_ws;
  unsigned short* Kw  = Qw  + 8388608;
  unsigned short* Vw  = Kw  + 8388608;
  unsigned short* XA  = Vw  + 8388608;    // Xb (pre-attn) then AO (post-attn)
  unsigned short* WtQ = XA  + 8388608;
  unsigned short* WtO = WtQ + 786432;
  unsigned short* relt= WtO + 262144;
  const bool useT = ws_size >= (34603008ULL + 33554432ULL) * 2ULL;  // base + rel table

  k_convert_x<<<dim3(4096), dim3(256), 0, stream>>>(x, XA);
  k_transpose_w<<<dim3(16, 48), dim3(256), 0, stream>>>(Wqkv, WtQ, 1536);
  k_transpose_w<<<dim3(16, 16), dim3(256), 0, stream>>>(Wout, WtO, 512);
  if (useT) k_relconv<<<dim3(32768), dim3(256), 0, stream>>>(rel, relt);
  k_gemm<0><<<dim3(128, 12), dim3(256), 0, stream>>>(XA, WtQ, bqkv, nullptr, Qw, Kw, Vw);
  if (useT) k_attn<true ><<<dim3(2048), dim3(256), 0, stream>>>(Qw, Kw, Vw, rel, relt, XA);
  else      k_attn<false><<<dim3(2048), dim3(256), 0, stream>>>(Qw, Kw, Vw, rel, relt, XA);
  k_gemm<1><<<dim3(128, 4), dim3(256), 0, stream>>>(XA, WtO, bout, out, nullptr, nullptr, nullptr);
}

// Round 15
// 213.615 us; speedup vs baseline: 1.1183x; 1.1183x over previous
//
#include <hip/hip_runtime.h>
#include <cstdint>

// CausalSelfAttention fused pipeline, all-bf16 MFMA path.
// R15 = R14's grid (2048 blocks; block = 4 waves = 4 batches of one (h,q16) slab,
// big-first, h=bid&7 XCD-pins relt; waves share relt tiles via L1 — FETCH 290->75MB
// confirmed) + R13's register discipline: __launch_bounds__(256,4). R14's (256,6)
// squeezed the allocator to the 40-VGPR tier and spilled 65MB/dispatch; the R13
// body emits ~60 VGPR at (256,4), which is UNDER the 64-reg/8-waves-per-EU HW tier —
// runtime residency follows actual usage, so the 8192-wave grid can fill 32 waves/CU.
// ws layout (ushort): Qf[8.39M] Kf[8.39M] Vf[8.39M] XbAO[8.39M] WtQ[786K] WtO[262K] [relt 33.55M]

#define DEVI __device__ __forceinline__

typedef __bf16 bf8 __attribute__((ext_vector_type(8)));
typedef float f4 __attribute__((ext_vector_type(4)));
typedef unsigned short us8 __attribute__((ext_vector_type(8)));
typedef unsigned short us4 __attribute__((ext_vector_type(4)));

typedef const unsigned int __attribute__((address_space(1))) gu32;
typedef unsigned int __attribute__((address_space(3))) lu32;

DEVI unsigned short f2bf(float f) {  // RNE f32->bf16 (prep/GEMM epilogues)
  unsigned u = __builtin_bit_cast(unsigned, f);
  u += 0x7fffu + ((u >> 16) & 1u);
  return (unsigned short)(u >> 16);
}

DEVI unsigned short cbf(float f) {   // compiler-lowered cast (v_cvt_pk_bf16_f32 pairs)
  return __builtin_bit_cast(unsigned short, (__bf16)f);
}

DEVI void gl_lds16(const void* g, void* l) {
  __builtin_amdgcn_global_load_lds((gu32*)g, (lu32*)l, 16, 0, 0);
}

DEVI bf8 comb(us4 a, us4 b) {
  us8 r;
  r[0]=a[0]; r[1]=a[1]; r[2]=a[2]; r[3]=a[3];
  r[4]=b[0]; r[5]=b[1]; r[6]=b[2]; r[7]=b[3];
  return __builtin_bit_cast(bf8, r);
}

// ---------------- prep: x (f32 [16384][512]) -> bf16, chunk-swizzled ----------------
__global__ __launch_bounds__(256) void k_convert_x(const float* __restrict__ x,
                                                   unsigned short* __restrict__ xb) {
  int c = blockIdx.x * 256 + threadIdx.x;   // 1,048,576 chunks
  int row = c >> 6, cl = c & 63;
  const float* s = x + ((size_t)row << 9) + (cl << 3);
  float4 a = *(const float4*)s;
  float4 b = *(const float4*)(s + 4);
  us8 o;
  o[0]=f2bf(a.x); o[1]=f2bf(a.y); o[2]=f2bf(a.z); o[3]=f2bf(a.w);
  o[4]=f2bf(b.x); o[5]=f2bf(b.y); o[6]=f2bf(b.z); o[7]=f2bf(b.w);
  int p = (cl & ~7) | ((cl & 7) ^ (row & 7));
  *(us8*)(xb + ((size_t)row << 9) + (p << 3)) = o;
}

// ------------- prep: W [512][N] f32 -> Wt [N][512] bf16, chunk-swizzled -------------
__global__ __launch_bounds__(256) void k_transpose_w(const float* __restrict__ W,
                                                     unsigned short* __restrict__ Wt, int N) {
  __shared__ float t[32][33];
  int k0 = blockIdx.x * 32, n0 = blockIdx.y * 32;
  int tx = threadIdx.x & 31, ty = threadIdx.x >> 5;
#pragma unroll
  for (int r = 0; r < 4; ++r)
    t[ty + r * 8][tx] = W[(size_t)(k0 + ty + r * 8) * N + n0 + tx];
  __syncthreads();
#pragma unroll
  for (int r = 0; r < 4; ++r) {
    int n = n0 + ty + r * 8, k = k0 + tx;
    int k2 = (k & ~63) | ((((k >> 3) & 7) ^ (n & 7)) << 3) | (k & 7);
    Wt[((size_t)n << 9) + k2] = f2bf(t[tx][ty + r * 8]);
  }
}

// ---- prep: rel f32 [h][q][k] -> bf16 fragment-ordered table (lower-tri tiles only) ----
__global__ __launch_bounds__(256) void k_relconv(const float* __restrict__ rel,
                                                 unsigned short* __restrict__ relt) {
  int t = blockIdx.x * 256 + threadIdx.x;   // 8.39M threads
  int lane = t & 63, ct = (t >> 6) & 3, kt = (t >> 8) & 31, q16 = (t >> 13) & 127, h = t >> 20;
  if (kt > (q16 >> 2)) return;              // above-diagonal tiles never read
  int row0 = (q16 << 4) + ((lane >> 4) << 2);
  int col = (kt << 6) + (ct << 4) + (lane & 15);
  const float* rp = rel + ((size_t)h << 22) + ((size_t)row0 << 11) + col;
  us4 o;
#pragma unroll
  for (int j = 0; j < 4; ++j) o[j] = f2bf(rp[(size_t)j << 11]);
  size_t idx = ((((((size_t)h << 7) | q16) << 5) | kt) << 2 | ct) << 6 | lane;
  *(us4*)(relt + (idx << 2)) = o;
}

// ---------------- GEMM: C[M][col] = A[M][512] * Bt[col][512]^T + bias ----------------
template <int EPI>
__global__ __launch_bounds__(256, 2)
void k_gemm(const unsigned short* __restrict__ Ag, const unsigned short* __restrict__ Bg,
            const float* __restrict__ bias, float* __restrict__ Of,
            unsigned short* __restrict__ Oq, unsigned short* __restrict__ Ok,
            unsigned short* __restrict__ Ov) {
  __shared__ __align__(16) unsigned short lds[128 * 64 * 2];
  unsigned short* Al = lds;
  unsigned short* Bl = lds + 128 * 64;
  const int tid = threadIdx.x, wv = tid >> 6, lane = tid & 63, g = lane >> 4, cl = lane & 15;
  const int wm = wv >> 1, wn = wv & 1;
  const int row0 = blockIdx.x * 128, col0 = blockIdx.y * 128;
  f4 acc[4][4];
#pragma unroll
  for (int i = 0; i < 4; ++i)
#pragma unroll
    for (int j = 0; j < 4; ++j) acc[i][j] = (f4){0.f, 0.f, 0.f, 0.f};

  for (int kt = 0; kt < 8; ++kt) {
#pragma unroll
    for (int j = 0; j < 4; ++j) {
      int ci = wv * 4 + j;
      int gci = ci * 64 + lane;
      int r = gci >> 3, cc = gci & 7;
      gl_lds16(Ag + ((size_t)(row0 + r) << 9) + kt * 64 + cc * 8, Al + ci * 512);
      gl_lds16(Bg + ((size_t)(col0 + r) << 9) + kt * 64 + cc * 8, Bl + ci * 512);
    }
    __syncthreads();
#pragma unroll
    for (int kk = 0; kk < 2; ++kk) {
      bf8 af[4], bb[4];
#pragma unroll
      for (int mf = 0; mf < 4; ++mf) {
        int r = wm * 64 + mf * 16 + cl;
        int cc = (kk * 4 + g) ^ (r & 7);
        af[mf] = *(const bf8*)(Al + r * 64 + cc * 8);
      }
#pragma unroll
      for (int nf = 0; nf < 4; ++nf) {
        int r = wn * 64 + nf * 16 + cl;
        int cc = (kk * 4 + g) ^ (r & 7);
        bb[nf] = *(const bf8*)(Bl + r * 64 + cc * 8);
      }
#pragma unroll
      for (int mf = 0; mf < 4; ++mf)
#pragma unroll
        for (int nf = 0; nf < 4; ++nf)
          acc[mf][nf] = __builtin_amdgcn_mfma_f32_16x16x32_bf16(af[mf], bb[nf], acc[mf][nf], 0, 0, 0);
    }
    __syncthreads();
  }

  if (EPI == 1) {
#pragma unroll
    for (int nf = 0; nf < 4; ++nf) {
      int col = col0 + wn * 64 + nf * 16 + cl;
      float bv = bias[col];
#pragma unroll
      for (int mf = 0; mf < 4; ++mf) {
#pragma unroll
        for (int j = 0; j < 4; ++j) {
          int row = row0 + wm * 64 + mf * 16 + 4 * g + j;  // C/D: col=lane&15, row=4*(lane>>4)+reg
          Of[((size_t)row << 9) + col] = acc[mf][nf][j] + bv;
        }
      }
    }
  } else {
    const int which = col0 >> 9;   // block-uniform
#pragma unroll
    for (int nf = 0; nf < 4; ++nf) {
      int col = col0 + wn * 64 + nf * 16 + cl;
      float bv = bias[col];
      int d = col & 63, h = (col >> 6) & 7;
#pragma unroll
      for (int mf = 0; mf < 4; ++mf) {
        int row = row0 + wm * 64 + mf * 16 + 4 * g;   // j = 0 row
        int b = row >> 11, s = row & 2047;
        size_t fb = ((size_t)b * 8 + h) * 131072;     // per-(b,h) fragment array
        if (which == 0) {
          // Q frag: [q16][kk][lane][8]; val = Q[s=q16*16+cl][d=kk*32+g*8+j]
#pragma unroll
          for (int j = 0; j < 4; ++j) {
            int ss = s + j;
            size_t off = fb + (size_t)((ss >> 4) * 1024 + (d >> 5) * 512 +
                                       (((d >> 3) & 3) * 16 + (ss & 15)) * 8 + (d & 7));
            Oq[off] = f2bf((acc[mf][nf][j] + bv) * 0.125f);   // fold softmax scale
          }
        } else if (which == 1) {
          // K frag: [kt][kk][ct][lane][8]; val = K[s=kt*64+ct*16+cl][d=kk*32+g*8+j]
#pragma unroll
          for (int j = 0; j < 4; ++j) {
            int ss = s + j;
            size_t off = fb + (size_t)((ss >> 6) * 4096 + (d >> 5) * 2048 + ((ss >> 4) & 3) * 512 +
                                       (((d >> 3) & 3) * 16 + (ss & 15)) * 8 + (d & 7));
            Ok[off] = f2bf(acc[mf][nf][j] + bv);
          }
        } else {
          // V frag: [kt][kk][ct][lane][8]; val = V[s=kt*64+kk*32+g*8+j][d=ct*16+cl]
          us4 o;
#pragma unroll
          for (int j = 0; j < 4; ++j) o[j] = f2bf(acc[mf][nf][j] + bv);
          size_t off = fb + (size_t)((s >> 6) * 4096 + ((s >> 5) & 1) * 2048 + (d >> 4) * 512 +
                                     ((((s >> 3) & 3) * 16) + (d & 15)) * 8 + (s & 7));
          *(us4*)(Ov + off) = o;
        }
      }
    }
  }
}

// ------------------------------- flash attention --------------------------------
// block = 4 waves = 4 BATCHES of the same (h, q16) slab; 2048 blocks big-first.
// Each wave: one q16 slab, k-tiles 0..(q16>>2). relt tiles identical across the
// block's 4 waves (L1-shared). Loads at tile top (K then V then rel, FIFO vmcnt).
// launch_bounds(256,4): budget 128, body emits ~60 VGPR (R13-measured) -> HW
// residency reaches 8 waves/EU because usage < 64-reg tier. Do NOT raise the bound.
template <bool RELT>
__global__ __launch_bounds__(256, 4)
void k_attn(const unsigned short* __restrict__ Qf, const unsigned short* __restrict__ Kf,
            const unsigned short* __restrict__ Vf, const float* __restrict__ rel,
            const unsigned short* __restrict__ relt, unsigned short* __restrict__ AO) {
  __shared__ __align__(16) unsigned short Pl[4][16 * 68];
  const int tid = threadIdx.x, wv = tid >> 6, lane = tid & 63, g = lane >> 4, cl = lane & 15;
  // decode: h = bid&7 (all blocks of head h share bid%8 -> one XCD holds relt[h]);
  // q16 big-first; wave's batch = (rest&1)*4 + wv.
  int bid = blockIdx.x;                        // 2048 blocks
  int h = bid & 7;
  int rest = bid >> 3;                         // 0..255
  int q16 = 127 - (rest >> 1);                 // 127..0, big-first
  int b = ((rest & 1) << 2) | wv;              // 0..7
  const int rX = q16 << 4;
  const int ktop = q16 >> 2;                   // diagonal k-tile index
  size_t fb = (((size_t)b << 3) + h) * 131072;
  const unsigned short* Qp = Qf + fb;
  const unsigned short* Kp = Kf + fb;
  const unsigned short* Vp = Vf + fb;
  const float* relp = rel + ((size_t)h << 22);
  unsigned short* pw = Pl[wv];

  bf8 qf[2];
#pragma unroll
  for (int kk = 0; kk < 2; ++kk)
    qf[kk] = *(const bf8*)(Qp + q16 * 1024 + kk * 512 + lane * 8);

  f4 oa[4];
  float mr[4], lr[4];
#pragma unroll
  for (int j = 0; j < 4; ++j) { mr[j] = -1e30f; lr[j] = 0.f; }
#pragma unroll
  for (int ct = 0; ct < 4; ++ct) oa[ct] = (f4){0.f, 0.f, 0.f, 0.f};

  for (int kt = 0; kt <= ktop; ++kt) {
    const int kb = kt << 6;
    const unsigned short* Kt = Kp + kt * 4096;
    const unsigned short* Vt = Vp + kt * 4096;
    // ---- ALL loads up front: K (QK^T dep), then V, then rel (FIFO vmcnt) ----
    bf8 kf[2][4], vf[2][4];
#pragma unroll
    for (int kk = 0; kk < 2; ++kk)
#pragma unroll
      for (int ct = 0; ct < 4; ++ct)
        kf[kk][ct] = *(const bf8*)(Kt + kk * 2048 + ct * 512 + lane * 8);
#pragma unroll
    for (int kk = 0; kk < 2; ++kk)
#pragma unroll
      for (int ct = 0; ct < 4; ++ct)
        vf[kk][ct] = *(const bf8*)(Vt + kk * 2048 + ct * 512 + lane * 8);
    us4 rt4[4];
    float rl[4][4];
    if constexpr (RELT) {
      const unsigned short* tb = relt + (((((size_t)h << 7) | q16) << 5) | kt) * 1024;
#pragma unroll
      for (int ct = 0; ct < 4; ++ct)
        rt4[ct] = *(const us4*)(tb + ((ct << 6) | lane) * 4);
    } else {
      const float* rb = relp + ((size_t)(rX + 4 * g) << 11) + kb + cl;
#pragma unroll
      for (int ct = 0; ct < 4; ++ct)
#pragma unroll
        for (int j = 0; j < 4; ++j) rl[ct][j] = rb[((size_t)j << 11) + ct * 16];
    }
    // ---- QK^T (waits on kf only) ----
    f4 sa[4];
#pragma unroll
    for (int ct = 0; ct < 4; ++ct) sa[ct] = (f4){0.f, 0.f, 0.f, 0.f};
#pragma unroll
    for (int kk = 0; kk < 2; ++kk)
#pragma unroll
      for (int ct = 0; ct < 4; ++ct)
        sa[ct] = __builtin_amdgcn_mfma_f32_16x16x32_bf16(qf[kk], kf[kk][ct], sa[ct], 0, 0, 0);
    // ---- rel_pos add ----
    if constexpr (RELT) {
#pragma unroll
      for (int ct = 0; ct < 4; ++ct)
#pragma unroll
        for (int j = 0; j < 4; ++j)
          sa[ct][j] += __builtin_bit_cast(float, (unsigned)rt4[ct][j] << 16);
    } else {
#pragma unroll
      for (int ct = 0; ct < 4; ++ct)
#pragma unroll
        for (int j = 0; j < 4; ++j) sa[ct][j] += rl[ct][j];
    }
    // ---- causal mask (diagonal tile only) ----
    if (kt == ktop) {
#pragma unroll
      for (int ct = 0; ct < 4; ++ct) {
        int kcol = kb + ct * 16 + cl;
#pragma unroll
        for (int j = 0; j < 4; ++j)
          if (kcol > rX + 4 * g + j) sa[ct][j] = -1e30f;
      }
    }
    // ---- online softmax (rows in 16-lane groups) ----
    float al[4];
#pragma unroll
    for (int j = 0; j < 4; ++j) {
      float m0 = fmaxf(fmaxf(sa[0][j], sa[1][j]), fmaxf(sa[2][j], sa[3][j]));
      m0 = fmaxf(m0, __shfl_xor(m0, 1, 16));
      m0 = fmaxf(m0, __shfl_xor(m0, 2, 16));
      m0 = fmaxf(m0, __shfl_xor(m0, 4, 16));
      m0 = fmaxf(m0, __shfl_xor(m0, 8, 16));
      float mn = fmaxf(mr[j], m0);
      al[j] = __expf(mr[j] - mn);
      mr[j] = mn;
    }
#pragma unroll
    for (int ct = 0; ct < 4; ++ct)
#pragma unroll
      for (int j = 0; j < 4; ++j) sa[ct][j] = __expf(sa[ct][j] - mr[j]);
#pragma unroll
    for (int j = 0; j < 4; ++j) {
      float rs = sa[0][j] + sa[1][j] + sa[2][j] + sa[3][j];
      rs += __shfl_xor(rs, 1, 16);
      rs += __shfl_xor(rs, 2, 16);
      rs += __shfl_xor(rs, 4, 16);
      rs += __shfl_xor(rs, 8, 16);
      lr[j] = lr[j] * al[j] + rs;
    }
#pragma unroll
    for (int ct = 0; ct < 4; ++ct) {
      oa[ct][0] *= al[0]; oa[ct][1] *= al[1]; oa[ct][2] *= al[2]; oa[ct][3] *= al[3];
    }
    // ---- P -> LDS transpose (wave-private; compiler cvt_pk pairs) ----
#pragma unroll
    for (int ct = 0; ct < 4; ++ct)
#pragma unroll
      for (int j = 0; j < 4; ++j)
        pw[(4 * g + j) * 68 + ct * 16 + cl] = cbf(sa[ct][j]);
    // ---- PV (vf already resident) ----
#pragma unroll
    for (int kk = 0; kk < 2; ++kk) {
      us4 p0 = *(const us4*)(pw + cl * 68 + kk * 32 + g * 8);
      us4 p1 = *(const us4*)(pw + cl * 68 + kk * 32 + g * 8 + 4);
      bf8 pf = comb(p0, p1);
#pragma unroll
      for (int ct = 0; ct < 4; ++ct)
        oa[ct] = __builtin_amdgcn_mfma_f32_16x16x32_bf16(pf, vf[kk][ct], oa[ct], 0, 0, 0);
    }
  }
  // ---- epilogue: O /= l, chunk-swizzled bf16 write ----
#pragma unroll
  for (int j = 0; j < 4; ++j) {
    float inv = 1.0f / lr[j];
    int s = rX + 4 * g + j;
#pragma unroll
    for (int ct = 0; ct < 4; ++ct) {
      int d = ct * 16 + cl;
      int d2 = (d & 7) | (((d >> 3) ^ (s & 7)) << 3);
      AO[(((size_t)b << 11) + s) * 512 + h * 64 + d2] = cbf(oa[ct][j] * inv);
    }
  }
}

// ------------------------------------ launch ------------------------------------
extern "C" void kernel_launch(void* const* d_in, const int* in_sizes, int n_in,
                              void* d_out, int out_size, void* d_ws, size_t ws_size,
                              hipStream_t stream) {
  const float* x    = (const float*)d_in[0];
  const float* Wqkv = (const float*)d_in[1];
  const float* bqkv = (const float*)d_in[2];
  const float* Wout = (const float*)d_in[3];
  const float* bout = (const float*)d_in[4];
  const float* rel  = (const float*)d_in[5];
  float* out = (float*)d_out;

  unsigned short* Qw  = (unsigned short*)d_ws;
  unsigned short* Kw  = Qw  + 8388608;
  unsigned short* Vw  = Kw  + 8388608;
  unsigned short* XA  = Vw  + 8388608;    // Xb (pre-attn) then AO (post-attn)
  unsigned short* WtQ = XA  + 8388608;
  unsigned short* WtO = WtQ + 786432;
  unsigned short* relt= WtO + 262144;
  const bool useT = ws_size >= (34603008ULL + 33554432ULL) * 2ULL;  // base + rel table

  k_convert_x<<<dim3(4096), dim3(256), 0, stream>>>(x, XA);
  k_transpose_w<<<dim3(16, 48), dim3(256), 0, stream>>>(Wqkv, WtQ, 1536);
  k_transpose_w<<<dim3(16, 16), dim3(256), 0, stream>>>(Wout, WtO, 512);
  if (useT) k_relconv<<<dim3(32768), dim3(256), 0, stream>>>(rel, relt);
  k_gemm<0><<<dim3(128, 12), dim3(256), 0, stream>>>(XA, WtQ, bqkv, nullptr, Qw, Kw, Vw);
  if (useT) k_attn<true ><<<dim3(2048), dim3(256), 0, stream>>>(Qw, Kw, Vw, rel, relt, XA);
  else      k_attn<false><<<dim3(2048), dim3(256), 0, stream>>>(Qw, Kw, Vw, rel, relt, XA);
  k_gemm<1><<<dim3(128, 4), dim3(256), 0, stream>>>(XA, WtO, bout, out, nullptr, nullptr, nullptr);
}

// Round 16
// 213.005 us; speedup vs baseline: 1.1215x; 1.0029x over previous
//
#include <hip/hip_runtime.h>
#include <cstdint>

// CausalSelfAttention fused pipeline, all-bf16 MFMA path.
// R16 = R13's structure (1024 blocks, sequential two-pass complementary pairs,
// uniform 33 tiles/block) with a SWAPPED-QK^T tile body (T12 adapted to 16x16):
// mfma(K,Q) makes each lane own one q-row -> softmax is in-lane (2 shfl vs 32),
// m/l are lane scalars, P goes through LDS as [q][k] rows (4 ds_write_b64 +
// 2 ds_read_b128 vs 16+4 scalar ops), PV is mfma(V,P) with existing V storage.
// LDS-pipe ops per tile: 52 -> 10. rel table transposed accordingly.
// ws layout (ushort): Qf[8.39M] Kf[8.39M] Vf[8.39M] XbAO[8.39M] WtQ[786K] WtO[262K] [relt 33.55M]

#define DEVI __device__ __forceinline__

typedef __bf16 bf8 __attribute__((ext_vector_type(8)));
typedef float f4 __attribute__((ext_vector_type(4)));
typedef unsigned short us8 __attribute__((ext_vector_type(8)));
typedef unsigned short us4 __attribute__((ext_vector_type(4)));

typedef const unsigned int __attribute__((address_space(1))) gu32;
typedef unsigned int __attribute__((address_space(3))) lu32;

DEVI unsigned short f2bf(float f) {  // RNE f32->bf16 (prep/GEMM epilogues)
  unsigned u = __builtin_bit_cast(unsigned, f);
  u += 0x7fffu + ((u >> 16) & 1u);
  return (unsigned short)(u >> 16);
}

DEVI unsigned short cbf(float f) {   // compiler-lowered cast (v_cvt_pk_bf16_f32 pairs)
  return __builtin_bit_cast(unsigned short, (__bf16)f);
}

DEVI void gl_lds16(const void* g, void* l) {
  __builtin_amdgcn_global_load_lds((gu32*)g, (lu32*)l, 16, 0, 0);
}

// ---------------- prep: x (f32 [16384][512]) -> bf16, chunk-swizzled ----------------
__global__ __launch_bounds__(256) void k_convert_x(const float* __restrict__ x,
                                                   unsigned short* __restrict__ xb) {
  int c = blockIdx.x * 256 + threadIdx.x;   // 1,048,576 chunks
  int row = c >> 6, cl = c & 63;
  const float* s = x + ((size_t)row << 9) + (cl << 3);
  float4 a = *(const float4*)s;
  float4 b = *(const float4*)(s + 4);
  us8 o;
  o[0]=f2bf(a.x); o[1]=f2bf(a.y); o[2]=f2bf(a.z); o[3]=f2bf(a.w);
  o[4]=f2bf(b.x); o[5]=f2bf(b.y); o[6]=f2bf(b.z); o[7]=f2bf(b.w);
  int p = (cl & ~7) | ((cl & 7) ^ (row & 7));
  *(us8*)(xb + ((size_t)row << 9) + (p << 3)) = o;
}

// ------------- prep: W [512][N] f32 -> Wt [N][512] bf16, chunk-swizzled -------------
__global__ __launch_bounds__(256) void k_transpose_w(const float* __restrict__ W,
                                                     unsigned short* __restrict__ Wt, int N) {
  __shared__ float t[32][33];
  int k0 = blockIdx.x * 32, n0 = blockIdx.y * 32;
  int tx = threadIdx.x & 31, ty = threadIdx.x >> 5;
#pragma unroll
  for (int r = 0; r < 4; ++r)
    t[ty + r * 8][tx] = W[(size_t)(k0 + ty + r * 8) * N + n0 + tx];
  __syncthreads();
#pragma unroll
  for (int r = 0; r < 4; ++r) {
    int n = n0 + ty + r * 8, k = k0 + tx;
    int k2 = (k & ~63) | ((((k >> 3) & 7) ^ (n & 7)) << 3) | (k & 7);
    Wt[((size_t)n << 9) + k2] = f2bf(t[tx][ty + r * 8]);
  }
}

// ---- prep: rel f32 [h][q][k] -> bf16 table in SWAPPED fragment order ----
// relt[h][q16][kt][ct][lane][j] = rel[q16*16 + (lane&15)][kt*64 + ct*16 + 4*(lane>>4) + j]
__global__ __launch_bounds__(256) void k_relconv(const float* __restrict__ rel,
                                                 unsigned short* __restrict__ relt) {
  int t = blockIdx.x * 256 + threadIdx.x;   // 8.39M threads
  int lane = t & 63, ct = (t >> 6) & 3, kt = (t >> 8) & 31, q16 = (t >> 13) & 127, h = t >> 20;
  if (kt > (q16 >> 2)) return;              // above-diagonal tiles never read
  int row = (q16 << 4) + (lane & 15);
  int col = (kt << 6) + (ct << 4) + ((lane >> 4) << 2);
  float4 v = *(const float4*)(rel + ((size_t)h << 22) + ((size_t)row << 11) + col);
  us4 o;
  o[0] = f2bf(v.x); o[1] = f2bf(v.y); o[2] = f2bf(v.z); o[3] = f2bf(v.w);
  size_t idx = ((((((size_t)h << 7) | q16) << 5) | kt) << 2 | ct) << 6 | lane;
  *(us4*)(relt + (idx << 2)) = o;
}

// ---------------- GEMM: C[M][col] = A[M][512] * Bt[col][512]^T + bias ----------------
template <int EPI>
__global__ __launch_bounds__(256, 2)
void k_gemm(const unsigned short* __restrict__ Ag, const unsigned short* __restrict__ Bg,
            const float* __restrict__ bias, float* __restrict__ Of,
            unsigned short* __restrict__ Oq, unsigned short* __restrict__ Ok,
            unsigned short* __restrict__ Ov) {
  __shared__ __align__(16) unsigned short lds[128 * 64 * 2];
  unsigned short* Al = lds;
  unsigned short* Bl = lds + 128 * 64;
  const int tid = threadIdx.x, wv = tid >> 6, lane = tid & 63, g = lane >> 4, cl = lane & 15;
  const int wm = wv >> 1, wn = wv & 1;
  const int row0 = blockIdx.x * 128, col0 = blockIdx.y * 128;
  f4 acc[4][4];
#pragma unroll
  for (int i = 0; i < 4; ++i)
#pragma unroll
    for (int j = 0; j < 4; ++j) acc[i][j] = (f4){0.f, 0.f, 0.f, 0.f};

  for (int kt = 0; kt < 8; ++kt) {
#pragma unroll
    for (int j = 0; j < 4; ++j) {
      int ci = wv * 4 + j;
      int gci = ci * 64 + lane;
      int r = gci >> 3, cc = gci & 7;
      gl_lds16(Ag + ((size_t)(row0 + r) << 9) + kt * 64 + cc * 8, Al + ci * 512);
      gl_lds16(Bg + ((size_t)(col0 + r) << 9) + kt * 64 + cc * 8, Bl + ci * 512);
    }
    __syncthreads();
#pragma unroll
    for (int kk = 0; kk < 2; ++kk) {
      bf8 af[4], bb[4];
#pragma unroll
      for (int mf = 0; mf < 4; ++mf) {
        int r = wm * 64 + mf * 16 + cl;
        int cc = (kk * 4 + g) ^ (r & 7);
        af[mf] = *(const bf8*)(Al + r * 64 + cc * 8);
      }
#pragma unroll
      for (int nf = 0; nf < 4; ++nf) {
        int r = wn * 64 + nf * 16 + cl;
        int cc = (kk * 4 + g) ^ (r & 7);
        bb[nf] = *(const bf8*)(Bl + r * 64 + cc * 8);
      }
#pragma unroll
      for (int mf = 0; mf < 4; ++mf)
#pragma unroll
        for (int nf = 0; nf < 4; ++nf)
          acc[mf][nf] = __builtin_amdgcn_mfma_f32_16x16x32_bf16(af[mf], bb[nf], acc[mf][nf], 0, 0, 0);
    }
    __syncthreads();
  }

  if (EPI == 1) {
#pragma unroll
    for (int nf = 0; nf < 4; ++nf) {
      int col = col0 + wn * 64 + nf * 16 + cl;
      float bv = bias[col];
#pragma unroll
      for (int mf = 0; mf < 4; ++mf) {
#pragma unroll
        for (int j = 0; j < 4; ++j) {
          int row = row0 + wm * 64 + mf * 16 + 4 * g + j;  // C/D: col=lane&15, row=4*(lane>>4)+reg
          Of[((size_t)row << 9) + col] = acc[mf][nf][j] + bv;
        }
      }
    }
  } else {
    const int which = col0 >> 9;   // block-uniform
#pragma unroll
    for (int nf = 0; nf < 4; ++nf) {
      int col = col0 + wn * 64 + nf * 16 + cl;
      float bv = bias[col];
      int d = col & 63, h = (col >> 6) & 7;
#pragma unroll
      for (int mf = 0; mf < 4; ++mf) {
        int row = row0 + wm * 64 + mf * 16 + 4 * g;   // j = 0 row
        int b = row >> 11, s = row & 2047;
        size_t fb = ((size_t)b * 8 + h) * 131072;     // per-(b,h) fragment array
        if (which == 0) {
          // Q frag: [q16][kk][lane][8]; val = Q[s=q16*16+cl][d=kk*32+g*8+j]
#pragma unroll
          for (int j = 0; j < 4; ++j) {
            int ss = s + j;
            size_t off = fb + (size_t)((ss >> 4) * 1024 + (d >> 5) * 512 +
                                       (((d >> 3) & 3) * 16 + (ss & 15)) * 8 + (d & 7));
            Oq[off] = f2bf((acc[mf][nf][j] + bv) * 0.125f);   // fold softmax scale
          }
        } else if (which == 1) {
          // K frag: [kt][kk][ct][lane][8]; val = K[s=kt*64+ct*16+cl][d=kk*32+g*8+j]
#pragma unroll
          for (int j = 0; j < 4; ++j) {
            int ss = s + j;
            size_t off = fb + (size_t)((ss >> 6) * 4096 + (d >> 5) * 2048 + ((ss >> 4) & 3) * 512 +
                                       (((d >> 3) & 3) * 16 + (ss & 15)) * 8 + (d & 7));
            Ok[off] = f2bf(acc[mf][nf][j] + bv);
          }
        } else {
          // V frag: [kt][kk][ct][lane][8]; val = V[s=kt*64+kk*32+g*8+j][d=ct*16+cl]
          us4 o;
#pragma unroll
          for (int j = 0; j < 4; ++j) o[j] = f2bf(acc[mf][nf][j] + bv);
          size_t off = fb + (size_t)((s >> 6) * 4096 + ((s >> 5) & 1) * 2048 + (d >> 4) * 512 +
                                     ((((s >> 3) & 3) * 16) + (d & 15)) * 8 + (s & 7));
          *(us4*)(Ov + off) = o;
        }
      }
    }
  }
}

// ------------------------------- flash attention --------------------------------
// block = (b, h, pair i); TWO SEQUENTIAL passes (slab i then 31-i), uniform 33 tiles.
// SWAPPED tile body: st = mfma(K,Q) -> lane owns q-row (q=cl), k=16ct+4g+j.
// Softmax: in-lane trees + 2 shfl; m/l lane scalars. P via LDS [q][k] rows
// (stride 72 halfwords): 4 ds_write_b64 + 2 ds_read_b128. PV: ot = mfma(V,P).
template <bool RELT>
__global__ __launch_bounds__(256, 4)
void k_attn(const unsigned short* __restrict__ Qf, const unsigned short* __restrict__ Kf,
            const unsigned short* __restrict__ Vf, const float* __restrict__ rel,
            const unsigned short* __restrict__ relt, unsigned short* __restrict__ AO) {
  __shared__ __align__(16) unsigned short Pl[4][16 * 72];
  const int tid = threadIdx.x, wv = tid >> 6, lane = tid & 63, g = lane >> 4, cl = lane & 15;
  // XCD swizzle: the 8 batches sharing relt panel (h,i) have equal bid%8 -> same XCD L2.
  int bid = blockIdx.x;                        // 1024 uniform blocks
  int glo = bid & 7, b = (bid >> 3) & 7, chi = bid >> 6;
  int c = chi * 8 + glo;                       // 0..127
  int h = c >> 4, i = c & 15;                  // pair index i = 0..15
  size_t fb = (((size_t)b << 3) + h) * 131072;
  const unsigned short* Qp = Qf + fb;
  const unsigned short* Kp = Kf + fb;
  const unsigned short* Vp = Vf + fb;
  const float* relp = rel + ((size_t)h << 22);
  unsigned short* pw = Pl[wv];

  for (int pass = 0; pass < 2; ++pass) {
    const int slab = pass ? (31 - i) : i;      // 0..31
    const int q16 = 4 * slab + wv;
    const int rX = q16 << 4;
    const int ktop = slab;                     // diagonal k-tile index
    const int qrow = rX + cl;                  // this lane's q-row (swapped layout)

    bf8 qf[2];
#pragma unroll
    for (int kk = 0; kk < 2; ++kk)
      qf[kk] = *(const bf8*)(Qp + q16 * 1024 + kk * 512 + lane * 8);

    f4 ot[4];                                  // O^T frags: ot[ct][j] = O[q=cl][d=16ct+4g+j]
    float mr = -1e30f, lr = 0.f;
#pragma unroll
    for (int ct = 0; ct < 4; ++ct) ot[ct] = (f4){0.f, 0.f, 0.f, 0.f};

    for (int kt = 0; kt <= ktop; ++kt) {
      const int kb = kt << 6;
      const unsigned short* Kt = Kp + kt * 4096;
      const unsigned short* Vt = Vp + kt * 4096;
      // ---- ALL loads up front: K (QK^T dep), then V, then rel (FIFO vmcnt) ----
      bf8 kf[2][4], vf[2][4];
#pragma unroll
      for (int kk = 0; kk < 2; ++kk)
#pragma unroll
        for (int ct = 0; ct < 4; ++ct)
          kf[kk][ct] = *(const bf8*)(Kt + kk * 2048 + ct * 512 + lane * 8);
#pragma unroll
      for (int kk = 0; kk < 2; ++kk)
#pragma unroll
        for (int ct = 0; ct < 4; ++ct)
          vf[kk][ct] = *(const bf8*)(Vt + kk * 2048 + ct * 512 + lane * 8);
      us4 rt4[4];
      float4 rl4[4];
      if constexpr (RELT) {
        const unsigned short* tb = relt + (((((size_t)h << 7) | q16) << 5) | kt) * 1024;
#pragma unroll
        for (int ct = 0; ct < 4; ++ct)
          rt4[ct] = *(const us4*)(tb + ((ct << 6) | lane) * 4);
      } else {
#pragma unroll
        for (int ct = 0; ct < 4; ++ct)
          rl4[ct] = *(const float4*)(relp + ((size_t)qrow << 11) + kb + ct * 16 + g * 4);
      }
      // ---- QK^T SWAPPED: st[ct][j] = S[q=cl][k = kb + 16ct + 4g + j] ----
      f4 st[4];
#pragma unroll
      for (int ct = 0; ct < 4; ++ct) st[ct] = (f4){0.f, 0.f, 0.f, 0.f};
#pragma unroll
      for (int kk = 0; kk < 2; ++kk)
#pragma unroll
        for (int ct = 0; ct < 4; ++ct)
          st[ct] = __builtin_amdgcn_mfma_f32_16x16x32_bf16(kf[kk][ct], qf[kk], st[ct], 0, 0, 0);
      // ---- rel_pos add ----
      if constexpr (RELT) {
#pragma unroll
        for (int ct = 0; ct < 4; ++ct)
#pragma unroll
          for (int j = 0; j < 4; ++j)
            st[ct][j] += __builtin_bit_cast(float, (unsigned)rt4[ct][j] << 16);
      } else {
#pragma unroll
        for (int ct = 0; ct < 4; ++ct) {
          st[ct][0] += rl4[ct].x; st[ct][1] += rl4[ct].y;
          st[ct][2] += rl4[ct].z; st[ct][3] += rl4[ct].w;
        }
      }
      // ---- causal mask (diagonal tile only) ----
      if (kt == ktop) {
#pragma unroll
        for (int ct = 0; ct < 4; ++ct) {
          int kc0 = kb + ct * 16 + 4 * g;
#pragma unroll
          for (int j = 0; j < 4; ++j)
            if (kc0 + j > qrow) st[ct][j] = -1e30f;
        }
      }
      // ---- online softmax: in-lane tree + 2 shfl across g-groups; lane scalars ----
      float m0 = fmaxf(fmaxf(st[0][0], st[0][1]), fmaxf(st[0][2], st[0][3]));
#pragma unroll
      for (int ct = 1; ct < 4; ++ct)
        m0 = fmaxf(m0, fmaxf(fmaxf(st[ct][0], st[ct][1]), fmaxf(st[ct][2], st[ct][3])));
      m0 = fmaxf(m0, __shfl_xor(m0, 16));
      m0 = fmaxf(m0, __shfl_xor(m0, 32));
      float mn = fmaxf(mr, m0);
      float al = __expf(mr - mn);
      mr = mn;
#pragma unroll
      for (int ct = 0; ct < 4; ++ct)
#pragma unroll
        for (int j = 0; j < 4; ++j) st[ct][j] = __expf(st[ct][j] - mn);
      float rs = 0.f;
#pragma unroll
      for (int ct = 0; ct < 4; ++ct)
        rs += (st[ct][0] + st[ct][1]) + (st[ct][2] + st[ct][3]);
      rs += __shfl_xor(rs, 16);
      rs += __shfl_xor(rs, 32);
      lr = lr * al + rs;
#pragma unroll
      for (int ct = 0; ct < 4; ++ct) {
        ot[ct][0] *= al; ot[ct][1] *= al; ot[ct][2] *= al; ot[ct][3] *= al;
      }
      // ---- P -> LDS rows [q=cl][k]: 4x ds_write_b64 (wave-private, in-order) ----
#pragma unroll
      for (int ct = 0; ct < 4; ++ct) {
        us4 pk;
        pk[0] = cbf(st[ct][0]); pk[1] = cbf(st[ct][1]);
        pk[2] = cbf(st[ct][2]); pk[3] = cbf(st[ct][3]);
        *(us4*)(pw + cl * 72 + ct * 16 + g * 4) = pk;
      }
      // ---- PV SWAPPED: ot[ct] += mfma(V_frag, P_frag); P read = B-frag b128 ----
#pragma unroll
      for (int kk = 0; kk < 2; ++kk) {
        bf8 pf = __builtin_bit_cast(bf8, *(const us8*)(pw + cl * 72 + kk * 32 + g * 8));
#pragma unroll
        for (int ct = 0; ct < 4; ++ct)
          ot[ct] = __builtin_amdgcn_mfma_f32_16x16x32_bf16(vf[kk][ct], pf, ot[ct], 0, 0, 0);
      }
    }
    // ---- epilogue: O /= l; d = 16ct+4g+j -> chunk-swizzled us4 stores ----
    float inv = 1.0f / lr;
    const int s = qrow;
    unsigned short* aor = AO + (((size_t)b << 11) + s) * 512 + h * 64;
#pragma unroll
    for (int ct = 0; ct < 4; ++ct) {
      int chunk = 2 * ct + (g >> 1);
      int base = (4 * (g & 1)) | ((chunk ^ (s & 7)) << 3);
      us4 o;
      o[0] = cbf(ot[ct][0] * inv); o[1] = cbf(ot[ct][1] * inv);
      o[2] = cbf(ot[ct][2] * inv); o[3] = cbf(ot[ct][3] * inv);
      *(us4*)(aor + base) = o;
    }
  }
}

// ------------------------------------ launch ------------------------------------
extern "C" void kernel_launch(void* const* d_in, const int* in_sizes, int n_in,
                              void* d_out, int out_size, void* d_ws, size_t ws_size,
                              hipStream_t stream) {
  const float* x    = (const float*)d_in[0];
  const float* Wqkv = (const float*)d_in[1];
  const float* bqkv = (const float*)d_in[2];
  const float* Wout = (const float*)d_in[3];
  const float* bout = (const float*)d_in[4];
  const float* rel  = (const float*)d_in[5];
  float* out = (float*)d_out;

  unsigned short* Qw  = (unsigned short*)d_ws;
  unsigned short* Kw  = Qw  + 8388608;
  unsigned short* Vw  = Kw  + 8388608;
  unsigned short* XA  = Vw  + 8388608;    // Xb (pre-attn) then AO (post-attn)
  unsigned short* WtQ = XA  + 8388608;
  unsigned short* WtO = WtQ + 786432;
  unsigned short* relt= WtO + 262144;
  const bool useT = ws_size >= (34603008ULL + 33554432ULL) * 2ULL;  // base + rel table

  k_convert_x<<<dim3(4096), dim3(256), 0, stream>>>(x, XA);
  k_transpose_w<<<dim3(16, 48), dim3(256), 0, stream>>>(Wqkv, WtQ, 1536);
  k_transpose_w<<<dim3(16, 16), dim3(256), 0, stream>>>(Wout, WtO, 512);
  if (useT) k_relconv<<<dim3(32768), dim3(256), 0, stream>>>(rel, relt);
  k_gemm<0><<<dim3(128, 12), dim3(256), 0, stream>>>(XA, WtQ, bqkv, nullptr, Qw, Kw, Vw);
  if (useT) k_attn<true ><<<dim3(1024), dim3(256), 0, stream>>>(Qw, Kw, Vw, rel, relt, XA);
  else      k_attn<false><<<dim3(1024), dim3(256), 0, stream>>>(Qw, Kw, Vw, rel, relt, XA);
  k_gemm<1><<<dim3(128, 4), dim3(256), 0, stream>>>(XA, WtO, bout, out, nullptr, nullptr, nullptr);
}

// Round 17
// 200.311 us; speedup vs baseline: 1.1926x; 1.0634x over previous
//
#include <hip/hip_runtime.h>
#include <cstdint>

// CausalSelfAttention fused pipeline, all-bf16 MFMA path.
// R17 = R16's SWAPPED-QK^T tile body (validated: lane owns q-row, in-lane softmax,
// 10 LDS-pipe ops/tile) + R15's grid (block = 4 waves = 4 batches of ONE (h,q16)
// slab; 2048 blocks big-first; h=bid&7 XCD-pins relt). R16xR13-grid re-exposed
// 322MB of relt re-fetch (HBM 36%, L2 thrash); R15 grid measured 50MB because the
// block's 4 waves read IDENTICAL relt tiles (L1 broadcast).
// ws layout (ushort): Qf[8.39M] Kf[8.39M] Vf[8.39M] XbAO[8.39M] WtQ[786K] WtO[262K] [relt 33.55M]

#define DEVI __device__ __forceinline__

typedef __bf16 bf8 __attribute__((ext_vector_type(8)));
typedef float f4 __attribute__((ext_vector_type(4)));
typedef unsigned short us8 __attribute__((ext_vector_type(8)));
typedef unsigned short us4 __attribute__((ext_vector_type(4)));

typedef const unsigned int __attribute__((address_space(1))) gu32;
typedef unsigned int __attribute__((address_space(3))) lu32;

DEVI unsigned short f2bf(float f) {  // RNE f32->bf16 (prep/GEMM epilogues)
  unsigned u = __builtin_bit_cast(unsigned, f);
  u += 0x7fffu + ((u >> 16) & 1u);
  return (unsigned short)(u >> 16);
}

DEVI unsigned short cbf(float f) {   // compiler-lowered cast (v_cvt_pk_bf16_f32 pairs)
  return __builtin_bit_cast(unsigned short, (__bf16)f);
}

DEVI void gl_lds16(const void* g, void* l) {
  __builtin_amdgcn_global_load_lds((gu32*)g, (lu32*)l, 16, 0, 0);
}

// ---------------- prep: x (f32 [16384][512]) -> bf16, chunk-swizzled ----------------
__global__ __launch_bounds__(256) void k_convert_x(const float* __restrict__ x,
                                                   unsigned short* __restrict__ xb) {
  int c = blockIdx.x * 256 + threadIdx.x;   // 1,048,576 chunks
  int row = c >> 6, cl = c & 63;
  const float* s = x + ((size_t)row << 9) + (cl << 3);
  float4 a = *(const float4*)s;
  float4 b = *(const float4*)(s + 4);
  us8 o;
  o[0]=f2bf(a.x); o[1]=f2bf(a.y); o[2]=f2bf(a.z); o[3]=f2bf(a.w);
  o[4]=f2bf(b.x); o[5]=f2bf(b.y); o[6]=f2bf(b.z); o[7]=f2bf(b.w);
  int p = (cl & ~7) | ((cl & 7) ^ (row & 7));
  *(us8*)(xb + ((size_t)row << 9) + (p << 3)) = o;
}

// ------------- prep: W [512][N] f32 -> Wt [N][512] bf16, chunk-swizzled -------------
__global__ __launch_bounds__(256) void k_transpose_w(const float* __restrict__ W,
                                                     unsigned short* __restrict__ Wt, int N) {
  __shared__ float t[32][33];
  int k0 = blockIdx.x * 32, n0 = blockIdx.y * 32;
  int tx = threadIdx.x & 31, ty = threadIdx.x >> 5;
#pragma unroll
  for (int r = 0; r < 4; ++r)
    t[ty + r * 8][tx] = W[(size_t)(k0 + ty + r * 8) * N + n0 + tx];
  __syncthreads();
#pragma unroll
  for (int r = 0; r < 4; ++r) {
    int n = n0 + ty + r * 8, k = k0 + tx;
    int k2 = (k & ~63) | ((((k >> 3) & 7) ^ (n & 7)) << 3) | (k & 7);
    Wt[((size_t)n << 9) + k2] = f2bf(t[tx][ty + r * 8]);
  }
}

// ---- prep: rel f32 [h][q][k] -> bf16 table in SWAPPED fragment order ----
// relt[h][q16][kt][ct][lane][j] = rel[q16*16 + (lane&15)][kt*64 + ct*16 + 4*(lane>>4) + j]
__global__ __launch_bounds__(256) void k_relconv(const float* __restrict__ rel,
                                                 unsigned short* __restrict__ relt) {
  int t = blockIdx.x * 256 + threadIdx.x;   // 8.39M threads
  int lane = t & 63, ct = (t >> 6) & 3, kt = (t >> 8) & 31, q16 = (t >> 13) & 127, h = t >> 20;
  if (kt > (q16 >> 2)) return;              // above-diagonal tiles never read
  int row = (q16 << 4) + (lane & 15);
  int col = (kt << 6) + (ct << 4) + ((lane >> 4) << 2);
  float4 v = *(const float4*)(rel + ((size_t)h << 22) + ((size_t)row << 11) + col);
  us4 o;
  o[0] = f2bf(v.x); o[1] = f2bf(v.y); o[2] = f2bf(v.z); o[3] = f2bf(v.w);
  size_t idx = ((((((size_t)h << 7) | q16) << 5) | kt) << 2 | ct) << 6 | lane;
  *(us4*)(relt + (idx << 2)) = o;
}

// ---------------- GEMM: C[M][col] = A[M][512] * Bt[col][512]^T + bias ----------------
template <int EPI>
__global__ __launch_bounds__(256, 2)
void k_gemm(const unsigned short* __restrict__ Ag, const unsigned short* __restrict__ Bg,
            const float* __restrict__ bias, float* __restrict__ Of,
            unsigned short* __restrict__ Oq, unsigned short* __restrict__ Ok,
            unsigned short* __restrict__ Ov) {
  __shared__ __align__(16) unsigned short lds[128 * 64 * 2];
  unsigned short* Al = lds;
  unsigned short* Bl = lds + 128 * 64;
  const int tid = threadIdx.x, wv = tid >> 6, lane = tid & 63, g = lane >> 4, cl = lane & 15;
  const int wm = wv >> 1, wn = wv & 1;
  const int row0 = blockIdx.x * 128, col0 = blockIdx.y * 128;
  f4 acc[4][4];
#pragma unroll
  for (int i = 0; i < 4; ++i)
#pragma unroll
    for (int j = 0; j < 4; ++j) acc[i][j] = (f4){0.f, 0.f, 0.f, 0.f};

  for (int kt = 0; kt < 8; ++kt) {
#pragma unroll
    for (int j = 0; j < 4; ++j) {
      int ci = wv * 4 + j;
      int gci = ci * 64 + lane;
      int r = gci >> 3, cc = gci & 7;
      gl_lds16(Ag + ((size_t)(row0 + r) << 9) + kt * 64 + cc * 8, Al + ci * 512);
      gl_lds16(Bg + ((size_t)(col0 + r) << 9) + kt * 64 + cc * 8, Bl + ci * 512);
    }
    __syncthreads();
#pragma unroll
    for (int kk = 0; kk < 2; ++kk) {
      bf8 af[4], bb[4];
#pragma unroll
      for (int mf = 0; mf < 4; ++mf) {
        int r = wm * 64 + mf * 16 + cl;
        int cc = (kk * 4 + g) ^ (r & 7);
        af[mf] = *(const bf8*)(Al + r * 64 + cc * 8);
      }
#pragma unroll
      for (int nf = 0; nf < 4; ++nf) {
        int r = wn * 64 + nf * 16 + cl;
        int cc = (kk * 4 + g) ^ (r & 7);
        bb[nf] = *(const bf8*)(Bl + r * 64 + cc * 8);
      }
#pragma unroll
      for (int mf = 0; mf < 4; ++mf)
#pragma unroll
        for (int nf = 0; nf < 4; ++nf)
          acc[mf][nf] = __builtin_amdgcn_mfma_f32_16x16x32_bf16(af[mf], bb[nf], acc[mf][nf], 0, 0, 0);
    }
    __syncthreads();
  }

  if (EPI == 1) {
#pragma unroll
    for (int nf = 0; nf < 4; ++nf) {
      int col = col0 + wn * 64 + nf * 16 + cl;
      float bv = bias[col];
#pragma unroll
      for (int mf = 0; mf < 4; ++mf) {
#pragma unroll
        for (int j = 0; j < 4; ++j) {
          int row = row0 + wm * 64 + mf * 16 + 4 * g + j;  // C/D: col=lane&15, row=4*(lane>>4)+reg
          Of[((size_t)row << 9) + col] = acc[mf][nf][j] + bv;
        }
      }
    }
  } else {
    const int which = col0 >> 9;   // block-uniform
#pragma unroll
    for (int nf = 0; nf < 4; ++nf) {
      int col = col0 + wn * 64 + nf * 16 + cl;
      float bv = bias[col];
      int d = col & 63, h = (col >> 6) & 7;
#pragma unroll
      for (int mf = 0; mf < 4; ++mf) {
        int row = row0 + wm * 64 + mf * 16 + 4 * g;   // j = 0 row
        int b = row >> 11, s = row & 2047;
        size_t fb = ((size_t)b * 8 + h) * 131072;     // per-(b,h) fragment array
        if (which == 0) {
          // Q frag: [q16][kk][lane][8]; val = Q[s=q16*16+cl][d=kk*32+g*8+j]
#pragma unroll
          for (int j = 0; j < 4; ++j) {
            int ss = s + j;
            size_t off = fb + (size_t)((ss >> 4) * 1024 + (d >> 5) * 512 +
                                       (((d >> 3) & 3) * 16 + (ss & 15)) * 8 + (d & 7));
            Oq[off] = f2bf((acc[mf][nf][j] + bv) * 0.125f);   // fold softmax scale
          }
        } else if (which == 1) {
          // K frag: [kt][kk][ct][lane][8]; val = K[s=kt*64+ct*16+cl][d=kk*32+g*8+j]
#pragma unroll
          for (int j = 0; j < 4; ++j) {
            int ss = s + j;
            size_t off = fb + (size_t)((ss >> 6) * 4096 + (d >> 5) * 2048 + ((ss >> 4) & 3) * 512 +
                                       (((d >> 3) & 3) * 16 + (ss & 15)) * 8 + (d & 7));
            Ok[off] = f2bf(acc[mf][nf][j] + bv);
          }
        } else {
          // V frag: [kt][kk][ct][lane][8]; val = V[s=kt*64+kk*32+g*8+j][d=ct*16+cl]
          us4 o;
#pragma unroll
          for (int j = 0; j < 4; ++j) o[j] = f2bf(acc[mf][nf][j] + bv);
          size_t off = fb + (size_t)((s >> 6) * 4096 + ((s >> 5) & 1) * 2048 + (d >> 4) * 512 +
                                     ((((s >> 3) & 3) * 16) + (d & 15)) * 8 + (s & 7));
          *(us4*)(Ov + off) = o;
        }
      }
    }
  }
}

// ------------------------------- flash attention --------------------------------
// block = 4 waves = 4 BATCHES of the same (h, q16) slab; 2048 blocks big-first.
// SWAPPED tile body: st = mfma(K,Q) -> lane owns q-row (q=cl), k=16ct+4g+j.
// Softmax: in-lane trees + 2 shfl; m/l lane scalars. P via LDS [q][k] rows
// (stride 72 halfwords): 4 ds_write_b64 + 2 ds_read_b128. PV: ot = mfma(V,P).
// relt tiles identical across the block's 4 waves -> L1 broadcast.
template <bool RELT>
__global__ __launch_bounds__(256, 4)
void k_attn(const unsigned short* __restrict__ Qf, const unsigned short* __restrict__ Kf,
            const unsigned short* __restrict__ Vf, const float* __restrict__ rel,
            const unsigned short* __restrict__ relt, unsigned short* __restrict__ AO) {
  __shared__ __align__(16) unsigned short Pl[4][16 * 72];
  const int tid = threadIdx.x, wv = tid >> 6, lane = tid & 63, g = lane >> 4, cl = lane & 15;
  // decode: h = bid&7 (head's relt panel pinned to one XCD); q16 big-first;
  // wave's batch = (rest&1)*4 + wv — all 4 waves share (h, q16).
  int bid = blockIdx.x;                        // 2048 blocks
  int h = bid & 7;
  int rest = bid >> 3;                         // 0..255
  int q16 = 127 - (rest >> 1);                 // 127..0, big-first
  int b = ((rest & 1) << 2) | wv;              // 0..7
  const int rX = q16 << 4;
  const int ktop = q16 >> 2;                   // diagonal k-tile index
  const int qrow = rX + cl;                    // this lane's q-row (swapped layout)
  size_t fb = (((size_t)b << 3) + h) * 131072;
  const unsigned short* Qp = Qf + fb;
  const unsigned short* Kp = Kf + fb;
  const unsigned short* Vp = Vf + fb;
  const float* relp = rel + ((size_t)h << 22);
  unsigned short* pw = Pl[wv];

  bf8 qf[2];
#pragma unroll
  for (int kk = 0; kk < 2; ++kk)
    qf[kk] = *(const bf8*)(Qp + q16 * 1024 + kk * 512 + lane * 8);

  f4 ot[4];                                    // O^T frags: ot[ct][j] = O[q=cl][d=16ct+4g+j]
  float mr = -1e30f, lr = 0.f;
#pragma unroll
  for (int ct = 0; ct < 4; ++ct) ot[ct] = (f4){0.f, 0.f, 0.f, 0.f};

  for (int kt = 0; kt <= ktop; ++kt) {
    const int kb = kt << 6;
    const unsigned short* Kt = Kp + kt * 4096;
    const unsigned short* Vt = Vp + kt * 4096;
    // ---- ALL loads up front: K (QK^T dep), then V, then rel (FIFO vmcnt) ----
    bf8 kf[2][4], vf[2][4];
#pragma unroll
    for (int kk = 0; kk < 2; ++kk)
#pragma unroll
      for (int ct = 0; ct < 4; ++ct)
        kf[kk][ct] = *(const bf8*)(Kt + kk * 2048 + ct * 512 + lane * 8);
#pragma unroll
    for (int kk = 0; kk < 2; ++kk)
#pragma unroll
      for (int ct = 0; ct < 4; ++ct)
        vf[kk][ct] = *(const bf8*)(Vt + kk * 2048 + ct * 512 + lane * 8);
    us4 rt4[4];
    float4 rl4[4];
    if constexpr (RELT) {
      const unsigned short* tb = relt + (((((size_t)h << 7) | q16) << 5) | kt) * 1024;
#pragma unroll
      for (int ct = 0; ct < 4; ++ct)
        rt4[ct] = *(const us4*)(tb + ((ct << 6) | lane) * 4);
    } else {
#pragma unroll
      for (int ct = 0; ct < 4; ++ct)
        rl4[ct] = *(const float4*)(relp + ((size_t)qrow << 11) + kb + ct * 16 + g * 4);
    }
    // ---- QK^T SWAPPED: st[ct][j] = S[q=cl][k = kb + 16ct + 4g + j] ----
    f4 st[4];
#pragma unroll
    for (int ct = 0; ct < 4; ++ct) st[ct] = (f4){0.f, 0.f, 0.f, 0.f};
#pragma unroll
    for (int kk = 0; kk < 2; ++kk)
#pragma unroll
      for (int ct = 0; ct < 4; ++ct)
        st[ct] = __builtin_amdgcn_mfma_f32_16x16x32_bf16(kf[kk][ct], qf[kk], st[ct], 0, 0, 0);
    // ---- rel_pos add ----
    if constexpr (RELT) {
#pragma unroll
      for (int ct = 0; ct < 4; ++ct)
#pragma unroll
        for (int j = 0; j < 4; ++j)
          st[ct][j] += __builtin_bit_cast(float, (unsigned)rt4[ct][j] << 16);
    } else {
#pragma unroll
      for (int ct = 0; ct < 4; ++ct) {
        st[ct][0] += rl4[ct].x; st[ct][1] += rl4[ct].y;
        st[ct][2] += rl4[ct].z; st[ct][3] += rl4[ct].w;
      }
    }
    // ---- causal mask (diagonal tile only) ----
    if (kt == ktop) {
#pragma unroll
      for (int ct = 0; ct < 4; ++ct) {
        int kc0 = kb + ct * 16 + 4 * g;
#pragma unroll
        for (int j = 0; j < 4; ++j)
          if (kc0 + j > qrow) st[ct][j] = -1e30f;
      }
    }
    // ---- online softmax: in-lane tree + 2 shfl across g-groups; lane scalars ----
    float m0 = fmaxf(fmaxf(st[0][0], st[0][1]), fmaxf(st[0][2], st[0][3]));
#pragma unroll
    for (int ct = 1; ct < 4; ++ct)
      m0 = fmaxf(m0, fmaxf(fmaxf(st[ct][0], st[ct][1]), fmaxf(st[ct][2], st[ct][3])));
    m0 = fmaxf(m0, __shfl_xor(m0, 16));
    m0 = fmaxf(m0, __shfl_xor(m0, 32));
    float mn = fmaxf(mr, m0);
    float al = __expf(mr - mn);
    mr = mn;
#pragma unroll
    for (int ct = 0; ct < 4; ++ct)
#pragma unroll
      for (int j = 0; j < 4; ++j) st[ct][j] = __expf(st[ct][j] - mn);
    float rs = 0.f;
#pragma unroll
    for (int ct = 0; ct < 4; ++ct)
      rs += (st[ct][0] + st[ct][1]) + (st[ct][2] + st[ct][3]);
    rs += __shfl_xor(rs, 16);
    rs += __shfl_xor(rs, 32);
    lr = lr * al + rs;
#pragma unroll
    for (int ct = 0; ct < 4; ++ct) {
      ot[ct][0] *= al; ot[ct][1] *= al; ot[ct][2] *= al; ot[ct][3] *= al;
    }
    // ---- P -> LDS rows [q=cl][k]: 4x ds_write_b64 (wave-private, in-order) ----
#pragma unroll
    for (int ct = 0; ct < 4; ++ct) {
      us4 pk;
      pk[0] = cbf(st[ct][0]); pk[1] = cbf(st[ct][1]);
      pk[2] = cbf(st[ct][2]); pk[3] = cbf(st[ct][3]);
      *(us4*)(pw + cl * 72 + ct * 16 + g * 4) = pk;
    }
    // ---- PV SWAPPED: ot[ct] += mfma(V_frag, P_frag); P read = B-frag b128 ----
#pragma unroll
    for (int kk = 0; kk < 2; ++kk) {
      bf8 pf = __builtin_bit_cast(bf8, *(const us8*)(pw + cl * 72 + kk * 32 + g * 8));
#pragma unroll
      for (int ct = 0; ct < 4; ++ct)
        ot[ct] = __builtin_amdgcn_mfma_f32_16x16x32_bf16(vf[kk][ct], pf, ot[ct], 0, 0, 0);
    }
  }
  // ---- epilogue: O /= l; d = 16ct+4g+j -> chunk-swizzled us4 stores ----
  float inv = 1.0f / lr;
  const int s = qrow;
  unsigned short* aor = AO + (((size_t)b << 11) + s) * 512 + h * 64;
#pragma unroll
  for (int ct = 0; ct < 4; ++ct) {
    int chunk = 2 * ct + (g >> 1);
    int base = (4 * (g & 1)) | ((chunk ^ (s & 7)) << 3);
    us4 o;
    o[0] = cbf(ot[ct][0] * inv); o[1] = cbf(ot[ct][1] * inv);
    o[2] = cbf(ot[ct][2] * inv); o[3] = cbf(ot[ct][3] * inv);
    *(us4*)(aor + base) = o;
  }
}

// ------------------------------------ launch ------------------------------------
extern "C" void kernel_launch(void* const* d_in, const int* in_sizes, int n_in,
                              void* d_out, int out_size, void* d_ws, size_t ws_size,
                              hipStream_t stream) {
  const float* x    = (const float*)d_in[0];
  const float* Wqkv = (const float*)d_in[1];
  const float* bqkv = (const float*)d_in[2];
  const float* Wout = (const float*)d_in[3];
  const float* bout = (const float*)d_in[4];
  const float* rel  = (const float*)d_in[5];
  float* out = (float*)d_out;

  unsigned short* Qw  = (unsigned short*)d_ws;
  unsigned short* Kw  = Qw  + 8388608;
  unsigned short* Vw  = Kw  + 8388608;
  unsigned short* XA  = Vw  + 8388608;    // Xb (pre-attn) then AO (post-attn)
  unsigned short* WtQ = XA  + 8388608;
  unsigned short* WtO = WtQ + 786432;
  unsigned short* relt= WtO + 262144;
  const bool useT = ws_size >= (34603008ULL + 33554432ULL) * 2ULL;  // base + rel table

  k_convert_x<<<dim3(4096), dim3(256), 0, stream>>>(x, XA);
  k_transpose_w<<<dim3(16, 48), dim3(256), 0, stream>>>(Wqkv, WtQ, 1536);
  k_transpose_w<<<dim3(16, 16), dim3(256), 0, stream>>>(Wout, WtO, 512);
  if (useT) k_relconv<<<dim3(32768), dim3(256), 0, stream>>>(rel, relt);
  k_gemm<0><<<dim3(128, 12), dim3(256), 0, stream>>>(XA, WtQ, bqkv, nullptr, Qw, Kw, Vw);
  if (useT) k_attn<true ><<<dim3(2048), dim3(256), 0, stream>>>(Qw, Kw, Vw, rel, relt, XA);
  else      k_attn<false><<<dim3(2048), dim3(256), 0, stream>>>(Qw, Kw, Vw, rel, relt, XA);
  k_gemm<1><<<dim3(128, 4), dim3(256), 0, stream>>>(XA, WtO, bout, out, nullptr, nullptr, nullptr);
}